// Round 6
// baseline (350.984 us; speedup 1.0000x reference)
//
#include <hip/hip_runtime.h>
#include <hip/hip_bf16.h>

#define BB 16
#define NN 1024
#define DD 5
#define RH 8

typedef unsigned long long u64;
typedef unsigned int u32;
typedef __hip_bfloat16 bf16;

static __device__ __forceinline__ float tof(bf16 x) { return __bfloat162float(x); }
// runtime-dtype load: f32 storage if f==true else bf16
static __device__ __forceinline__ float ldf(const void* p, long long i, bool f) {
  return f ? ((const float*)p)[i] : tof(((const bf16*)p)[i]);
}

// flags: [0]=insane_cnt [1]=adj_non01 [2]=adj_nonpair [3]=adj_low3f80
#define N_PROBE_WORDS 8192

// ---------------------------------------------------------------- init
__global__ void k_init(int* flags) {
  if (threadIdx.x < 8) flags[threadIdx.x] = 0;
}

// ---------------------------------------------- fused dtype probes
__global__ void k_probe(const u32* __restrict__ fw, const u32* __restrict__ aw,
                        int adj_nwords, int* flags) {
  if (blockIdx.x < 32) {
    int i = blockIdx.x * 256 + threadIdx.x;
    if (i >= N_PROBE_WORDS) return;
    u32 lo = fw[i] & 0xFFFFu;
    int e = (int)((lo >> 7) & 0xFFu);
    bool sane = (lo == 0u) || (e >= 90 && e <= 150);
    u64 mask = __ballot(!sane);
    if ((threadIdx.x & 63) == 0) atomicAdd(&flags[0], (int)__popcll(mask));
  } else {
    int idx = (blockIdx.x - 32) * 256 + threadIdx.x;
    int stride = (gridDim.x - 32) * 256;
    int non01 = 0, nonpair = 0, low3 = 0;
    for (int i = idx; i < adj_nwords; i += stride) {
      u32 x = aw[i];
      u32 lo = x & 0xFFFFu, hi = x >> 16;
      non01 |= (x > 1u);
      nonpair |= !((lo == 0u || lo == 0x3F80u) && (hi == 0u || hi == 0x3F80u));
      low3 |= (lo == 0x3F80u);
    }
    if (non01) atomicOr(&flags[1], 1);
    if (nonpair) atomicOr(&flags[2], 1);
    if (low3) atomicOr(&flags[3], 1);
  }
}

// ---------------------------------------------------------------- pack
__global__ void k_pack(const void* __restrict__ adj, const int* __restrict__ flags,
                       u64* __restrict__ adjbits) {
  int gid = blockIdx.x * blockDim.x + threadIdx.x;
  if (gid >= BB * NN * 16) return;
  int w = gid & 15;
  long long row = gid >> 4;
  long long base = row * NN + (long long)w * 64;
  int mode;
  if (!flags[1]) mode = 0;
  else if (!flags[2]) mode = flags[3] ? 2 : 3;
  else mode = 1;
  u64 bits = 0;
  if (mode == 3) {
    const uint4* p = (const uint4*)((const float*)adj + base);
    #pragma unroll
    for (int t = 0; t < 16; ++t) {
      uint4 x = p[t];
      if (x.x << 1) bits |= 1ull << (4 * t + 0);
      if (x.y << 1) bits |= 1ull << (4 * t + 1);
      if (x.z << 1) bits |= 1ull << (4 * t + 2);
      if (x.w << 1) bits |= 1ull << (4 * t + 3);
    }
  } else if (mode == 0) {
    const uint4* p = (const uint4*)((const u32*)adj + base);
    #pragma unroll
    for (int t = 0; t < 16; ++t) {
      uint4 x = p[t];
      if (x.x) bits |= 1ull << (4 * t + 0);
      if (x.y) bits |= 1ull << (4 * t + 1);
      if (x.z) bits |= 1ull << (4 * t + 2);
      if (x.w) bits |= 1ull << (4 * t + 3);
    }
  } else if (mode == 2) {
    const uint4* p = (const uint4*)((const unsigned short*)adj + base);
    #pragma unroll
    for (int t = 0; t < 8; ++t) {
      uint4 x = p[t];
      u32 c[4] = {x.x, x.y, x.z, x.w};
      #pragma unroll
      for (int q = 0; q < 4; ++q) {
        if ((c[q] & 0x7FFFu)) bits |= 1ull << (8 * t + 2 * q + 0);
        if ((c[q] >> 16) & 0x7FFFu) bits |= 1ull << (8 * t + 2 * q + 1);
      }
    }
  } else {
    const uint4* p = (const uint4*)((const unsigned char*)adj + base);
    #pragma unroll
    for (int t = 0; t < 4; ++t) {
      uint4 x = p[t];
      u32 c[4] = {x.x, x.y, x.z, x.w};
      #pragma unroll
      for (int q = 0; q < 4; ++q)
        #pragma unroll
        for (int bb = 0; bb < 4; ++bb)
          if ((c[q] >> (8 * bb)) & 0xFFu) bits |= 1ull << (16 * t + 4 * q + bb);
    }
  }
  adjbits[gid] = bits;
}

// -------------------------------------------------------------- two-hop
__global__ __launch_bounds__(256) void k_twohop(const u64* __restrict__ adjbits,
                                                u64* __restrict__ neighbits) {
  __shared__ unsigned short listL[4][NN];
  int wave = threadIdx.x >> 6, lane = threadIdx.x & 63;
  int row = blockIdx.x * 4 + wave;
  int b = row >> 10;
  int i = row & (NN - 1);
  int w = lane & 15;
  const u64* rowp = adjbits + (size_t)row * 16;
  u64 rw = rowp[w];
  unsigned short* list = listL[wave];
  int cnt = 0;
  #pragma unroll
  for (int sw = 0; sw < 16; ++sw) {
    u64 bits = __shfl(rw, sw, 64);
    int mybit = (int)((bits >> lane) & 1ull);
    int pre = __popcll(bits & ((1ull << lane) - 1ull));
    if (mybit) list[cnt + pre] = (unsigned short)(sw * 64 + lane);
    cnt += __popcll(bits);
  }
  __syncthreads();
  u64 acc = rw;
  if (w == (i >> 6)) acc |= 1ull << (i & 63);
  int g = lane >> 4;
  const u64* basep = adjbits + (size_t)b * NN * 16;
  for (int n = g; n < cnt; n += 4) {
    int j = list[n];
    acc |= basep[(size_t)j * 16 + w];
  }
  acc |= __shfl_xor(acc, 16, 64);
  acc |= __shfl_xor(acc, 32, 64);
  if (lane < 16) neighbits[(size_t)row * 16 + lane] = acc;
}

// ------------------------------------------------------------- attention
// Block = (b, chunk of 32 rows, j-half of 512). 4 waves x 8 rows; each wave
// sweeps its block's 512-j half with DIRECT exp (no running max: scores are
// bounded |s| << 85; clamp + masked->-100 for inf-safety). Unnormalized
// (l, A) partials go to rowAgg[row][half]; k_final merges + normalizes.
__global__ __launch_bounds__(256, 3) void k_attn(
    const void* __restrict__ feats, const void* __restrict__ coors,
    const void* __restrict__ Wq, const void* __restrict__ Wk,
    const void* __restrict__ Wv, const void* __restrict__ Wo,
    const void* __restrict__ wr1, const void* __restrict__ br1,
    const void* __restrict__ wr2, const void* __restrict__ br2,
    const int* __restrict__ flags,
    const u64* __restrict__ neighbits, float* __restrict__ rowAgg) {
  __shared__ __align__(16) float4 kvL[512 * 3];  // 24 KB: k0..k4,v0..v4,pad,pad
  __shared__ float coL[512 * 3];                 // 6 KB
  __shared__ float wqL[25], wkL[25], wvL[25], woL[25];
  __shared__ float qL[32 * DD], ciL[32 * 3];
  __shared__ float wrL[3][RH];
  __shared__ float sConst[2];  // [0]=C (collapsed radial), [1]=b_r2
  __shared__ int sFast;
  int bi = blockIdx.x;
  int b = bi >> 6, rem = bi & 63, chunk = rem >> 1, half = rem & 1;
  int j0 = half * 512;
  int tid = threadIdx.x;
  bool f32 = flags[0] > (N_PROBE_WORDS / 4);
  if (tid < 25) {
    wqL[tid] = ldf(Wq, tid, f32);
    wkL[tid] = ldf(Wk, tid, f32);
    wvL[tid] = ldf(Wv, tid, f32);
    woL[tid] = ldf(Wo, tid, f32);
  }
  if (tid >= 64 && tid < 64 + RH) {
    int h = tid - 64;
    wrL[0][h] = ldf(wr1, h, f32);
    wrL[1][h] = ldf(br1, h, f32);
    wrL[2][h] = ldf(wr2, h, f32);
  }
  if (tid == 96) {
    float c = 0.0f;
    int ok = 1;
    #pragma unroll
    for (int h = 0; h < RH; ++h) {
      float w1h = ldf(wr1, h, f32);
      if (ldf(br1, h, f32) != 0.0f) ok = 0;
      if (w1h > 0.0f) c += w1h * ldf(wr2, h, f32);
    }
    sConst[0] = c;
    sConst[1] = ldf(br2, 0, f32);
    sFast = ok;
  }
  __syncthreads();
  // stage k, v' = (f@Wv)@Wo and co for this j-half
  for (int n = tid; n < 512; n += 256) {
    long long node = (long long)b * NN + j0 + n;
    float f0 = ldf(feats, node * DD + 0, f32), f1 = ldf(feats, node * DD + 1, f32),
          f2 = ldf(feats, node * DD + 2, f32), f3 = ldf(feats, node * DD + 3, f32),
          f4 = ldf(feats, node * DD + 4, f32);
    float k[DD], tv[DD], v[DD];
    #pragma unroll
    for (int e = 0; e < DD; ++e) {
      k[e] = f0 * wkL[e] + f1 * wkL[5 + e] + f2 * wkL[10 + e] + f3 * wkL[15 + e] +
             f4 * wkL[20 + e];
      tv[e] = f0 * wvL[e] + f1 * wvL[5 + e] + f2 * wvL[10 + e] + f3 * wvL[15 + e] +
              f4 * wvL[20 + e];
    }
    #pragma unroll
    for (int e = 0; e < DD; ++e)
      v[e] = tv[0] * woL[e] + tv[1] * woL[5 + e] + tv[2] * woL[10 + e] +
             tv[3] * woL[15 + e] + tv[4] * woL[20 + e];
    kvL[n * 3 + 0] = make_float4(k[0], k[1], k[2], k[3]);
    kvL[n * 3 + 1] = make_float4(k[4], v[0], v[1], v[2]);
    kvL[n * 3 + 2] = make_float4(v[3], v[4], 0.f, 0.f);
  }
  for (int idx = tid; idx < 512 * 3; idx += 256)
    coL[idx] = ldf(coors, (long long)(b * NN + j0) * 3 + idx, f32);
  if (tid < 32) {
    long long row = (long long)b * NN + chunk * 32 + tid;
    float f0 = ldf(feats, row * DD + 0, f32), f1 = ldf(feats, row * DD + 1, f32),
          f2 = ldf(feats, row * DD + 2, f32), f3 = ldf(feats, row * DD + 3, f32),
          f4 = ldf(feats, row * DD + 4, f32);
    #pragma unroll
    for (int e = 0; e < DD; ++e)
      qL[tid * DD + e] = (f0 * wqL[e] + f1 * wqL[5 + e] + f2 * wqL[10 + e] +
                          f3 * wqL[15 + e] + f4 * wqL[20 + e]) * 0.4472135954999579f;
    #pragma unroll
    for (int c = 0; c < 3; ++c) ciL[tid * 3 + c] = ldf(coors, row * 3 + c, f32);
  }
  __syncthreads();

  int g = tid >> 6, lane = tid & 63;
  int i0 = chunk * 32 + g * 8;
  float q[8][DD], ci[8][3], l[8], A[8][DD];
  #pragma unroll
  for (int r = 0; r < 8; ++r) {
    #pragma unroll
    for (int e = 0; e < DD; ++e) q[r][e] = qL[(g * 8 + r) * DD + e];
    #pragma unroll
    for (int c = 0; c < 3; ++c) ci[r][c] = ciL[(g * 8 + r) * 3 + c];
    l[r] = 0.0f;
    #pragma unroll
    for (int e = 0; e < DD; ++e) A[r][e] = 0.0f;
  }
  const u64* nb = neighbits + ((size_t)(b * NN + i0)) * 16 + half * 8;
  float Cf = sConst[0], br2f = sConst[1];
  int fast = sFast;
  for (int it = 0; it < 8; ++it) {
    int j = it * 64 + lane;
    float4 ka = kvL[j * 3 + 0];
    float4 kb = kvL[j * 3 + 1];
    float4 kc = kvL[j * 3 + 2];
    float jx = coL[j * 3], jy = coL[j * 3 + 1], jz = coL[j * 3 + 2];
    if (fast) {
      #pragma unroll
      for (int r = 0; r < 8; ++r) {
        u64 nw = nb[(size_t)r * 16 + it];
        float cx = jx - ci[r][0], cy = jy - ci[r][1], cz = jz - ci[r][2];
        float dist = sqrtf(fmaf(cx, cx, fmaf(cy, cy, fmaf(cz, cz, 1e-8f))));
        float s = fmaf(q[r][0], ka.x, br2f);
        s = fmaf(q[r][1], ka.y, s);
        s = fmaf(q[r][2], ka.z, s);
        s = fmaf(q[r][3], ka.w, s);
        s = fmaf(q[r][4], kb.x, s);
        s = fmaf(Cf, dist, s);
        s = fminf(s, 85.0f);
        s = ((nw >> lane) & 1ull) ? s : -100.0f;
        float p = __expf(s);
        l[r] += p;
        A[r][0] = fmaf(p, kb.y, A[r][0]);
        A[r][1] = fmaf(p, kb.z, A[r][1]);
        A[r][2] = fmaf(p, kb.w, A[r][2]);
        A[r][3] = fmaf(p, kc.x, A[r][3]);
        A[r][4] = fmaf(p, kc.y, A[r][4]);
      }
    } else {
      #pragma unroll
      for (int r = 0; r < 8; ++r) {
        u64 nw = nb[(size_t)r * 16 + it];
        float cx = jx - ci[r][0], cy = jy - ci[r][1], cz = jz - ci[r][2];
        float dist = sqrtf(fmaf(cx, cx, fmaf(cy, cy, fmaf(cz, cz, 1e-8f))));
        float rb = br2f;
        #pragma unroll
        for (int h = 0; h < RH; ++h)
          rb += fmaxf(dist * wrL[0][h] + wrL[1][h], 0.0f) * wrL[2][h];
        float s = fmaf(q[r][0], ka.x, rb);
        s = fmaf(q[r][1], ka.y, s);
        s = fmaf(q[r][2], ka.z, s);
        s = fmaf(q[r][3], ka.w, s);
        s = fmaf(q[r][4], kb.x, s);
        s = fminf(s, 85.0f);
        s = ((nw >> lane) & 1ull) ? s : -100.0f;
        float p = __expf(s);
        l[r] += p;
        A[r][0] = fmaf(p, kb.y, A[r][0]);
        A[r][1] = fmaf(p, kb.z, A[r][1]);
        A[r][2] = fmaf(p, kb.w, A[r][2]);
        A[r][3] = fmaf(p, kc.x, A[r][3]);
        A[r][4] = fmaf(p, kc.y, A[r][4]);
      }
    }
  }
  #pragma unroll
  for (int msk = 1; msk < 64; msk <<= 1) {
    #pragma unroll
    for (int r = 0; r < 8; ++r) {
      l[r] += __shfl_xor(l[r], msk, 64);
      A[r][0] += __shfl_xor(A[r][0], msk, 64);
      A[r][1] += __shfl_xor(A[r][1], msk, 64);
      A[r][2] += __shfl_xor(A[r][2], msk, 64);
      A[r][3] += __shfl_xor(A[r][3], msk, 64);
      A[r][4] += __shfl_xor(A[r][4], msk, 64);
    }
  }
  if (lane == 0) {
    #pragma unroll
    for (int r = 0; r < 8; ++r) {
      float* o = rowAgg + (((size_t)(b * NN + i0 + r)) * 2 + half) * 6;
      o[0] = l[r];
      o[1] = A[r][0]; o[2] = A[r][1]; o[3] = A[r][2]; o[4] = A[r][3]; o[5] = A[r][4];
    }
  }
}

// --------------------------------------------------- finalize: pool + MLP
__global__ __launch_bounds__(256) void k_final(
    const void* __restrict__ feats, const float* __restrict__ rowAgg,
    const int* __restrict__ flags,
    const void* __restrict__ w1, const void* __restrict__ b1,
    const void* __restrict__ w2, const void* __restrict__ b2,
    float* __restrict__ out) {
  __shared__ float waveL[4][DD];
  __shared__ float poolL[DD];
  __shared__ float hL[128];
  int b = blockIdx.x, tid = threadIdx.x;
  bool f32 = flags[0] > (N_PROBE_WORDS / 4);
  float pe[DD] = {0.f, 0.f, 0.f, 0.f, 0.f};
  for (int n = tid; n < NN; n += 256) {
    const float* ag = rowAgg + ((size_t)(b * NN + n)) * 12;
    float l = ag[0] + ag[6];
    float inv = (l > 0.f) ? 1.0f / l : 0.0f;
    long long base = ((long long)b * NN + n) * DD;
    #pragma unroll
    for (int e = 0; e < DD; ++e)
      pe[e] += ldf(feats, base + e, f32) + (ag[1 + e] + ag[7 + e]) * inv;
  }
  #pragma unroll
  for (int off = 32; off >= 1; off >>= 1)
    #pragma unroll
    for (int e = 0; e < DD; ++e) pe[e] += __shfl_down(pe[e], off, 64);
  int wave = tid >> 6, lane = tid & 63;
  if (lane == 0)
    #pragma unroll
    for (int e = 0; e < DD; ++e) waveL[wave][e] = pe[e];
  __syncthreads();
  if (tid < DD)
    poolL[tid] = (waveL[0][tid] + waveL[1][tid] + waveL[2][tid] + waveL[3][tid]) *
                 (1.0f / 1024.0f);
  __syncthreads();
  if (tid < 128) {
    float acc = ldf(b1, tid, f32);
    #pragma unroll
    for (int d = 0; d < DD; ++d)
      acc = fmaf(poolL[d], ldf(w1, d * 128 + tid, f32), acc);
    hL[tid] = fmaxf(acc, 0.0f);
  }
  __syncthreads();
  if (tid < 3) {
    float s = ldf(b2, tid, f32);
    for (int j = 0; j < 128; ++j) s = fmaf(hL[j], ldf(w2, j * 3 + tid, f32), s);
    out[b * 3 + tid] = s;
  }
}

// ---------------------------------------------------------------- launch
extern "C" void kernel_launch(void* const* d_in, const int* in_sizes, int n_in,
                              void* d_out, int out_size, void* d_ws, size_t ws_size,
                              hipStream_t stream) {
  const void* adj = d_in[2];
  float* out = (float*)d_out;

  char* w = (char*)d_ws;
  int* flags = (int*)w;
  const size_t BITS_BYTES = (size_t)BB * NN * 16 * sizeof(u64);  // 2 MiB
  u64* adjbits = (u64*)(w + 512);
  u64* neighbits = (u64*)(w + 512 + BITS_BYTES);
  float* rowAgg = (float*)(w + 512 + 2 * BITS_BYTES);  // B*N*2*6 f32 = 768 KiB

  k_init<<<1, 64, 0, stream>>>(flags);
  k_probe<<<32 + 512, 256, 0, stream>>>((const u32*)d_in[0], (const u32*)adj,
                                        1 << 20, flags);
  k_pack<<<BB * NN * 16 / 256, 256, 0, stream>>>(adj, flags, adjbits);
  k_twohop<<<BB * NN / 4, 256, 0, stream>>>(adjbits, neighbits);
  k_attn<<<BB * 64, 256, 0, stream>>>(d_in[0], d_in[1], d_in[3], d_in[4], d_in[5],
                                      d_in[6], d_in[7], d_in[8], d_in[9], d_in[10],
                                      flags, neighbits, rowAgg);
  k_final<<<BB, 256, 0, stream>>>(d_in[0], rowAgg, flags, d_in[11], d_in[12],
                                  d_in[13], d_in[14], out);
}

// Round 7
// 246.016 us; speedup vs baseline: 1.4267x; 1.4267x over previous
//
#include <hip/hip_runtime.h>
#include <hip/hip_bf16.h>

#define BB 16
#define NN 1024
#define DD 5
#define RH 8

typedef unsigned long long u64;
typedef unsigned int u32;
typedef __hip_bfloat16 bf16;

static __device__ __forceinline__ float tof(bf16 x) { return __bfloat162float(x); }
// runtime-dtype load: f32 storage if f==true else bf16
static __device__ __forceinline__ float ldf(const void* p, long long i, bool f) {
  return f ? ((const float*)p)[i] : tof(((const bf16*)p)[i]);
}

// flags: [0]=insane_cnt [1]=adj_non01 [2]=adj_nonpair [3]=adj_low3f80
#define N_PROBE_WORDS 8192

// ---------------------------------------------------------------- init
__global__ void k_init(int* flags) {
  if (threadIdx.x < 8) flags[threadIdx.x] = 0;
}

// ---------------------------------------------- fused dtype probes
__global__ void k_probe(const u32* __restrict__ fw, const u32* __restrict__ aw,
                        int adj_nwords, int* flags) {
  if (blockIdx.x < 32) {
    int i = blockIdx.x * 256 + threadIdx.x;
    if (i >= N_PROBE_WORDS) return;
    u32 lo = fw[i] & 0xFFFFu;
    int e = (int)((lo >> 7) & 0xFFu);
    bool sane = (lo == 0u) || (e >= 90 && e <= 150);
    u64 mask = __ballot(!sane);
    if ((threadIdx.x & 63) == 0) atomicAdd(&flags[0], (int)__popcll(mask));
  } else {
    int idx = (blockIdx.x - 32) * 256 + threadIdx.x;
    int stride = (gridDim.x - 32) * 256;
    int non01 = 0, nonpair = 0, low3 = 0;
    for (int i = idx; i < adj_nwords; i += stride) {
      u32 x = aw[i];
      u32 lo = x & 0xFFFFu, hi = x >> 16;
      non01 |= (x > 1u);
      nonpair |= !((lo == 0u || lo == 0x3F80u) && (hi == 0u || hi == 0x3F80u));
      low3 |= (lo == 0x3F80u);
    }
    if (non01) atomicOr(&flags[1], 1);
    if (nonpair) atomicOr(&flags[2], 1);
    if (low3) atomicOr(&flags[3], 1);
  }
}

// ---------------------------------------------------------------- pack
__global__ void k_pack(const void* __restrict__ adj, const int* __restrict__ flags,
                       u64* __restrict__ adjbits) {
  int gid = blockIdx.x * blockDim.x + threadIdx.x;
  if (gid >= BB * NN * 16) return;
  int w = gid & 15;
  long long row = gid >> 4;
  long long base = row * NN + (long long)w * 64;
  int mode;
  if (!flags[1]) mode = 0;
  else if (!flags[2]) mode = flags[3] ? 2 : 3;
  else mode = 1;
  u64 bits = 0;
  if (mode == 3) {
    const uint4* p = (const uint4*)((const float*)adj + base);
    #pragma unroll
    for (int t = 0; t < 16; ++t) {
      uint4 x = p[t];
      if (x.x << 1) bits |= 1ull << (4 * t + 0);
      if (x.y << 1) bits |= 1ull << (4 * t + 1);
      if (x.z << 1) bits |= 1ull << (4 * t + 2);
      if (x.w << 1) bits |= 1ull << (4 * t + 3);
    }
  } else if (mode == 0) {
    const uint4* p = (const uint4*)((const u32*)adj + base);
    #pragma unroll
    for (int t = 0; t < 16; ++t) {
      uint4 x = p[t];
      if (x.x) bits |= 1ull << (4 * t + 0);
      if (x.y) bits |= 1ull << (4 * t + 1);
      if (x.z) bits |= 1ull << (4 * t + 2);
      if (x.w) bits |= 1ull << (4 * t + 3);
    }
  } else if (mode == 2) {
    const uint4* p = (const uint4*)((const unsigned short*)adj + base);
    #pragma unroll
    for (int t = 0; t < 8; ++t) {
      uint4 x = p[t];
      u32 c[4] = {x.x, x.y, x.z, x.w};
      #pragma unroll
      for (int q = 0; q < 4; ++q) {
        if ((c[q] & 0x7FFFu)) bits |= 1ull << (8 * t + 2 * q + 0);
        if ((c[q] >> 16) & 0x7FFFu) bits |= 1ull << (8 * t + 2 * q + 1);
      }
    }
  } else {
    const uint4* p = (const uint4*)((const unsigned char*)adj + base);
    #pragma unroll
    for (int t = 0; t < 4; ++t) {
      uint4 x = p[t];
      u32 c[4] = {x.x, x.y, x.z, x.w};
      #pragma unroll
      for (int q = 0; q < 4; ++q)
        #pragma unroll
        for (int bb = 0; bb < 4; ++bb)
          if ((c[q] >> (8 * bb)) & 0xFFu) bits |= 1ull << (16 * t + 4 * q + bb);
    }
  }
  adjbits[gid] = bits;
}

// -------------------------------------------------------------- two-hop
__global__ __launch_bounds__(256) void k_twohop(const u64* __restrict__ adjbits,
                                                u64* __restrict__ neighbits) {
  __shared__ unsigned short listL[4][NN];
  int wave = threadIdx.x >> 6, lane = threadIdx.x & 63;
  int row = blockIdx.x * 4 + wave;
  int b = row >> 10;
  int i = row & (NN - 1);
  int w = lane & 15;
  const u64* rowp = adjbits + (size_t)row * 16;
  u64 rw = rowp[w];
  unsigned short* list = listL[wave];
  int cnt = 0;
  #pragma unroll
  for (int sw = 0; sw < 16; ++sw) {
    u64 bits = __shfl(rw, sw, 64);
    int mybit = (int)((bits >> lane) & 1ull);
    int pre = __popcll(bits & ((1ull << lane) - 1ull));
    if (mybit) list[cnt + pre] = (unsigned short)(sw * 64 + lane);
    cnt += __popcll(bits);
  }
  __syncthreads();
  u64 acc = rw;
  if (w == (i >> 6)) acc |= 1ull << (i & 63);
  int g = lane >> 4;
  const u64* basep = adjbits + (size_t)b * NN * 16;
  for (int n = g; n < cnt; n += 4) {
    int j = list[n];
    acc |= basep[(size_t)j * 16 + w];
  }
  acc |= __shfl_xor(acc, 16, 64);
  acc |= __shfl_xor(acc, 32, 64);
  if (lane < 16) neighbits[(size_t)row * 16 + lane] = acc;
}

// ------------------------------------------------------------- attention
// Block = (b, chunk of 16 rows, j-half of 512). 4 waves x 4 rows each.
// Direct exp (scores bounded; clamp 85, masked -> -100). Per-lane state =
// 4 rows x (q5+ci3+A5+l1) = 56 floats -> fits the 128-VGPR cap of
// __launch_bounds__(256,4) WITHOUT spilling (round-6's 8-row state under a
// (256,3) hint spilled to scratch: VGPR 84, 584 MB HBM, 189 us).
__global__ __launch_bounds__(256, 4) void k_attn(
    const void* __restrict__ feats, const void* __restrict__ coors,
    const void* __restrict__ Wq, const void* __restrict__ Wk,
    const void* __restrict__ Wv, const void* __restrict__ Wo,
    const void* __restrict__ wr1, const void* __restrict__ br1,
    const void* __restrict__ wr2, const void* __restrict__ br2,
    const int* __restrict__ flags,
    const u64* __restrict__ neighbits, float* __restrict__ rowAgg) {
  __shared__ __align__(16) float4 kvL[512 * 3];  // 24 KB: k0..k4,v0..v4,pad,pad
  __shared__ float coL[512 * 3];                 // 6 KB
  __shared__ float wqL[25], wkL[25], wvL[25], woL[25];
  __shared__ float qL[16 * DD], ciL[16 * 3];
  __shared__ float wrL[3][RH];
  __shared__ float sConst[2];  // [0]=C (collapsed radial), [1]=b_r2
  __shared__ int sFast;
  int bi = blockIdx.x;
  int b = bi >> 7, rem = bi & 127, chunk = rem >> 1, half = rem & 1;
  int j0 = half * 512;
  int tid = threadIdx.x;
  bool f32 = flags[0] > (N_PROBE_WORDS / 4);
  if (tid < 25) {
    wqL[tid] = ldf(Wq, tid, f32);
    wkL[tid] = ldf(Wk, tid, f32);
    wvL[tid] = ldf(Wv, tid, f32);
    woL[tid] = ldf(Wo, tid, f32);
  }
  if (tid >= 64 && tid < 64 + RH) {
    int h = tid - 64;
    wrL[0][h] = ldf(wr1, h, f32);
    wrL[1][h] = ldf(br1, h, f32);
    wrL[2][h] = ldf(wr2, h, f32);
  }
  if (tid == 96) {
    float c = 0.0f;
    int ok = 1;
    #pragma unroll
    for (int h = 0; h < RH; ++h) {
      float w1h = ldf(wr1, h, f32);
      if (ldf(br1, h, f32) != 0.0f) ok = 0;
      if (w1h > 0.0f) c += w1h * ldf(wr2, h, f32);
    }
    sConst[0] = c;
    sConst[1] = ldf(br2, 0, f32);
    sFast = ok;
  }
  __syncthreads();
  // stage k, v' = (f@Wv)@Wo and co for this j-half
  for (int n = tid; n < 512; n += 256) {
    long long node = (long long)b * NN + j0 + n;
    float f0 = ldf(feats, node * DD + 0, f32), f1 = ldf(feats, node * DD + 1, f32),
          f2 = ldf(feats, node * DD + 2, f32), f3 = ldf(feats, node * DD + 3, f32),
          f4 = ldf(feats, node * DD + 4, f32);
    float k[DD], tv[DD], v[DD];
    #pragma unroll
    for (int e = 0; e < DD; ++e) {
      k[e] = f0 * wkL[e] + f1 * wkL[5 + e] + f2 * wkL[10 + e] + f3 * wkL[15 + e] +
             f4 * wkL[20 + e];
      tv[e] = f0 * wvL[e] + f1 * wvL[5 + e] + f2 * wvL[10 + e] + f3 * wvL[15 + e] +
              f4 * wvL[20 + e];
    }
    #pragma unroll
    for (int e = 0; e < DD; ++e)
      v[e] = tv[0] * woL[e] + tv[1] * woL[5 + e] + tv[2] * woL[10 + e] +
             tv[3] * woL[15 + e] + tv[4] * woL[20 + e];
    kvL[n * 3 + 0] = make_float4(k[0], k[1], k[2], k[3]);
    kvL[n * 3 + 1] = make_float4(k[4], v[0], v[1], v[2]);
    kvL[n * 3 + 2] = make_float4(v[3], v[4], 0.f, 0.f);
  }
  for (int idx = tid; idx < 512 * 3; idx += 256)
    coL[idx] = ldf(coors, (long long)(b * NN + j0) * 3 + idx, f32);
  if (tid < 16) {
    long long row = (long long)b * NN + chunk * 16 + tid;
    float f0 = ldf(feats, row * DD + 0, f32), f1 = ldf(feats, row * DD + 1, f32),
          f2 = ldf(feats, row * DD + 2, f32), f3 = ldf(feats, row * DD + 3, f32),
          f4 = ldf(feats, row * DD + 4, f32);
    #pragma unroll
    for (int e = 0; e < DD; ++e)
      qL[tid * DD + e] = (f0 * wqL[e] + f1 * wqL[5 + e] + f2 * wqL[10 + e] +
                          f3 * wqL[15 + e] + f4 * wqL[20 + e]) * 0.4472135954999579f;
    #pragma unroll
    for (int c = 0; c < 3; ++c) ciL[tid * 3 + c] = ldf(coors, row * 3 + c, f32);
  }
  __syncthreads();

  int g = tid >> 6, lane = tid & 63;
  int i0 = chunk * 16 + g * 4;
  float q[4][DD], ci[4][3], l[4], A[4][DD];
  #pragma unroll
  for (int r = 0; r < 4; ++r) {
    #pragma unroll
    for (int e = 0; e < DD; ++e) q[r][e] = qL[(g * 4 + r) * DD + e];
    #pragma unroll
    for (int c = 0; c < 3; ++c) ci[r][c] = ciL[(g * 4 + r) * 3 + c];
    l[r] = 0.0f;
    #pragma unroll
    for (int e = 0; e < DD; ++e) A[r][e] = 0.0f;
  }
  const u64* nb = neighbits + ((size_t)(b * NN + i0)) * 16 + half * 8;
  float Cf = sConst[0], br2f = sConst[1];
  int fast = sFast;
  for (int it = 0; it < 8; ++it) {
    int j = it * 64 + lane;
    float4 ka = kvL[j * 3 + 0];
    float4 kb = kvL[j * 3 + 1];
    float4 kc = kvL[j * 3 + 2];
    float jx = coL[j * 3], jy = coL[j * 3 + 1], jz = coL[j * 3 + 2];
    if (fast) {
      #pragma unroll
      for (int r = 0; r < 4; ++r) {
        u64 nw = nb[(size_t)r * 16 + it];
        float cx = jx - ci[r][0], cy = jy - ci[r][1], cz = jz - ci[r][2];
        float dist = sqrtf(fmaf(cx, cx, fmaf(cy, cy, fmaf(cz, cz, 1e-8f))));
        float s = fmaf(q[r][0], ka.x, br2f);
        s = fmaf(q[r][1], ka.y, s);
        s = fmaf(q[r][2], ka.z, s);
        s = fmaf(q[r][3], ka.w, s);
        s = fmaf(q[r][4], kb.x, s);
        s = fmaf(Cf, dist, s);
        s = fminf(s, 85.0f);
        s = ((nw >> lane) & 1ull) ? s : -100.0f;
        float p = __expf(s);
        l[r] += p;
        A[r][0] = fmaf(p, kb.y, A[r][0]);
        A[r][1] = fmaf(p, kb.z, A[r][1]);
        A[r][2] = fmaf(p, kb.w, A[r][2]);
        A[r][3] = fmaf(p, kc.x, A[r][3]);
        A[r][4] = fmaf(p, kc.y, A[r][4]);
      }
    } else {
      #pragma unroll
      for (int r = 0; r < 4; ++r) {
        u64 nw = nb[(size_t)r * 16 + it];
        float cx = jx - ci[r][0], cy = jy - ci[r][1], cz = jz - ci[r][2];
        float dist = sqrtf(fmaf(cx, cx, fmaf(cy, cy, fmaf(cz, cz, 1e-8f))));
        float rb = br2f;
        #pragma unroll
        for (int h = 0; h < RH; ++h)
          rb += fmaxf(dist * wrL[0][h] + wrL[1][h], 0.0f) * wrL[2][h];
        float s = fmaf(q[r][0], ka.x, rb);
        s = fmaf(q[r][1], ka.y, s);
        s = fmaf(q[r][2], ka.z, s);
        s = fmaf(q[r][3], ka.w, s);
        s = fmaf(q[r][4], kb.x, s);
        s = fminf(s, 85.0f);
        s = ((nw >> lane) & 1ull) ? s : -100.0f;
        float p = __expf(s);
        l[r] += p;
        A[r][0] = fmaf(p, kb.y, A[r][0]);
        A[r][1] = fmaf(p, kb.z, A[r][1]);
        A[r][2] = fmaf(p, kb.w, A[r][2]);
        A[r][3] = fmaf(p, kc.x, A[r][3]);
        A[r][4] = fmaf(p, kc.y, A[r][4]);
      }
    }
  }
  #pragma unroll
  for (int msk = 1; msk < 64; msk <<= 1) {
    #pragma unroll
    for (int r = 0; r < 4; ++r) {
      l[r] += __shfl_xor(l[r], msk, 64);
      A[r][0] += __shfl_xor(A[r][0], msk, 64);
      A[r][1] += __shfl_xor(A[r][1], msk, 64);
      A[r][2] += __shfl_xor(A[r][2], msk, 64);
      A[r][3] += __shfl_xor(A[r][3], msk, 64);
      A[r][4] += __shfl_xor(A[r][4], msk, 64);
    }
  }
  if (lane == 0) {
    #pragma unroll
    for (int r = 0; r < 4; ++r) {
      float* o = rowAgg + (((size_t)(b * NN + i0 + r)) * 2 + half) * 6;
      o[0] = l[r];
      o[1] = A[r][0]; o[2] = A[r][1]; o[3] = A[r][2]; o[4] = A[r][3]; o[5] = A[r][4];
    }
  }
}

// --------------------------------------------------- finalize: pool + MLP
__global__ __launch_bounds__(256) void k_final(
    const void* __restrict__ feats, const float* __restrict__ rowAgg,
    const int* __restrict__ flags,
    const void* __restrict__ w1, const void* __restrict__ b1,
    const void* __restrict__ w2, const void* __restrict__ b2,
    float* __restrict__ out) {
  __shared__ float waveL[4][DD];
  __shared__ float poolL[DD];
  __shared__ float hL[128];
  int b = blockIdx.x, tid = threadIdx.x;
  bool f32 = flags[0] > (N_PROBE_WORDS / 4);
  float pe[DD] = {0.f, 0.f, 0.f, 0.f, 0.f};
  for (int n = tid; n < NN; n += 256) {
    const float* ag = rowAgg + ((size_t)(b * NN + n)) * 12;
    float l = ag[0] + ag[6];
    float inv = (l > 0.f) ? 1.0f / l : 0.0f;
    long long base = ((long long)b * NN + n) * DD;
    #pragma unroll
    for (int e = 0; e < DD; ++e)
      pe[e] += ldf(feats, base + e, f32) + (ag[1 + e] + ag[7 + e]) * inv;
  }
  #pragma unroll
  for (int off = 32; off >= 1; off >>= 1)
    #pragma unroll
    for (int e = 0; e < DD; ++e) pe[e] += __shfl_down(pe[e], off, 64);
  int wave = tid >> 6, lane = tid & 63;
  if (lane == 0)
    #pragma unroll
    for (int e = 0; e < DD; ++e) waveL[wave][e] = pe[e];
  __syncthreads();
  if (tid < DD)
    poolL[tid] = (waveL[0][tid] + waveL[1][tid] + waveL[2][tid] + waveL[3][tid]) *
                 (1.0f / 1024.0f);
  __syncthreads();
  if (tid < 128) {
    float acc = ldf(b1, tid, f32);
    #pragma unroll
    for (int d = 0; d < DD; ++d)
      acc = fmaf(poolL[d], ldf(w1, d * 128 + tid, f32), acc);
    hL[tid] = fmaxf(acc, 0.0f);
  }
  __syncthreads();
  if (tid < 3) {
    float s = ldf(b2, tid, f32);
    for (int j = 0; j < 128; ++j) s = fmaf(hL[j], ldf(w2, j * 3 + tid, f32), s);
    out[b * 3 + tid] = s;
  }
}

// ---------------------------------------------------------------- launch
extern "C" void kernel_launch(void* const* d_in, const int* in_sizes, int n_in,
                              void* d_out, int out_size, void* d_ws, size_t ws_size,
                              hipStream_t stream) {
  const void* adj = d_in[2];
  float* out = (float*)d_out;

  char* w = (char*)d_ws;
  int* flags = (int*)w;
  const size_t BITS_BYTES = (size_t)BB * NN * 16 * sizeof(u64);  // 2 MiB
  u64* adjbits = (u64*)(w + 512);
  u64* neighbits = (u64*)(w + 512 + BITS_BYTES);
  float* rowAgg = (float*)(w + 512 + 2 * BITS_BYTES);  // B*N*2*6 f32 = 768 KiB

  k_init<<<1, 64, 0, stream>>>(flags);
  k_probe<<<32 + 512, 256, 0, stream>>>((const u32*)d_in[0], (const u32*)adj,
                                        1 << 20, flags);
  k_pack<<<BB * NN * 16 / 256, 256, 0, stream>>>(adj, flags, adjbits);
  k_twohop<<<BB * NN / 4, 256, 0, stream>>>(adjbits, neighbits);
  k_attn<<<BB * 128, 256, 0, stream>>>(d_in[0], d_in[1], d_in[3], d_in[4], d_in[5],
                                       d_in[6], d_in[7], d_in[8], d_in[9], d_in[10],
                                       flags, neighbits, rowAgg);
  k_final<<<BB, 256, 0, stream>>>(d_in[0], rowAgg, flags, d_in[11], d_in[12],
                                  d_in[13], d_in[14], out);
}

// Round 8
// 202.196 us; speedup vs baseline: 1.7359x; 1.2167x over previous
//
#include <hip/hip_runtime.h>
#include <hip/hip_bf16.h>

#define BB 16
#define NN 1024
#define DD 5
#define RH 8

typedef unsigned long long u64;
typedef unsigned int u32;
typedef __hip_bfloat16 bf16;

static __device__ __forceinline__ float tof(bf16 x) { return __bfloat162float(x); }
// runtime-dtype load: f32 storage if f==true else bf16
static __device__ __forceinline__ float ldf(const void* p, long long i, bool f) {
  return f ? ((const float*)p)[i] : tof(((const bf16*)p)[i]);
}

// ---------------------------------------------------------------- pack
// adjbits[(b*N+i)*16 + w] = 64 adjacency bits. Storage mode (int32 / byte /
// bf16 / f32 bool) is probed per-block over the first 4096 words — same data
// and same rule in every block => globally consistent, no separate probe
// kernel or cross-kernel flag dependency.
__global__ __launch_bounds__(256) void k_pack(const void* __restrict__ adj,
                                              u64* __restrict__ adjbits) {
  __shared__ int sNon01, sNonpair, sLow3;
  int tid = threadIdx.x;
  if (tid == 0) { sNon01 = 0; sNonpair = 0; sLow3 = 0; }
  __syncthreads();
  {
    const u32* aw = (const u32*)adj;
    int non01 = 0, nonpair = 0, low3 = 0;
    for (int i = tid; i < 4096; i += 256) {
      u32 x = aw[i];
      u32 lo = x & 0xFFFFu, hi = x >> 16;
      non01 |= (x > 1u);
      nonpair |= !((lo == 0u || lo == 0x3F80u) && (hi == 0u || hi == 0x3F80u));
      low3 |= (lo == 0x3F80u);
    }
    if (non01) atomicOr(&sNon01, 1);
    if (nonpair) atomicOr(&sNonpair, 1);
    if (low3) atomicOr(&sLow3, 1);
  }
  __syncthreads();
  // mode: 0=int32, 1=byte, 2=bf16, 3=f32
  int mode;
  if (!sNon01) mode = 0;
  else if (!sNonpair) mode = sLow3 ? 2 : 3;
  else mode = 1;

  int gid = blockIdx.x * 256 + tid;
  if (gid >= BB * NN * 16) return;
  int w = gid & 15;
  long long row = gid >> 4;
  long long base = row * NN + (long long)w * 64;
  u64 bits = 0;
  if (mode == 3) {
    const uint4* p = (const uint4*)((const float*)adj + base);
    #pragma unroll
    for (int t = 0; t < 16; ++t) {
      uint4 x = p[t];
      if (x.x << 1) bits |= 1ull << (4 * t + 0);   // ignore -0.0
      if (x.y << 1) bits |= 1ull << (4 * t + 1);
      if (x.z << 1) bits |= 1ull << (4 * t + 2);
      if (x.w << 1) bits |= 1ull << (4 * t + 3);
    }
  } else if (mode == 0) {
    const uint4* p = (const uint4*)((const u32*)adj + base);
    #pragma unroll
    for (int t = 0; t < 16; ++t) {
      uint4 x = p[t];
      if (x.x) bits |= 1ull << (4 * t + 0);
      if (x.y) bits |= 1ull << (4 * t + 1);
      if (x.z) bits |= 1ull << (4 * t + 2);
      if (x.w) bits |= 1ull << (4 * t + 3);
    }
  } else if (mode == 2) {
    const uint4* p = (const uint4*)((const unsigned short*)adj + base);
    #pragma unroll
    for (int t = 0; t < 8; ++t) {
      uint4 x = p[t];
      u32 c[4] = {x.x, x.y, x.z, x.w};
      #pragma unroll
      for (int q = 0; q < 4; ++q) {
        if ((c[q] & 0x7FFFu)) bits |= 1ull << (8 * t + 2 * q + 0);
        if ((c[q] >> 16) & 0x7FFFu) bits |= 1ull << (8 * t + 2 * q + 1);
      }
    }
  } else {
    const uint4* p = (const uint4*)((const unsigned char*)adj + base);
    #pragma unroll
    for (int t = 0; t < 4; ++t) {
      uint4 x = p[t];
      u32 c[4] = {x.x, x.y, x.z, x.w};
      #pragma unroll
      for (int q = 0; q < 4; ++q)
        #pragma unroll
        for (int bb = 0; bb < 4; ++bb)
          if ((c[q] >> (8 * bb)) & 0xFFu) bits |= 1ull << (16 * t + 4 * q + bb);
    }
  }
  adjbits[gid] = bits;
}

// -------------------------------------------------------------- two-hop
__global__ __launch_bounds__(256) void k_twohop(const u64* __restrict__ adjbits,
                                                u64* __restrict__ neighbits) {
  __shared__ unsigned short listL[4][NN];
  int wave = threadIdx.x >> 6, lane = threadIdx.x & 63;
  int row = blockIdx.x * 4 + wave;
  int b = row >> 10;
  int i = row & (NN - 1);
  int w = lane & 15;
  const u64* rowp = adjbits + (size_t)row * 16;
  u64 rw = rowp[w];
  unsigned short* list = listL[wave];
  int cnt = 0;
  #pragma unroll
  for (int sw = 0; sw < 16; ++sw) {
    u64 bits = __shfl(rw, sw, 64);
    int mybit = (int)((bits >> lane) & 1ull);
    int pre = __popcll(bits & ((1ull << lane) - 1ull));
    if (mybit) list[cnt + pre] = (unsigned short)(sw * 64 + lane);
    cnt += __popcll(bits);
  }
  __syncthreads();
  u64 acc = rw;
  if (w == (i >> 6)) acc |= 1ull << (i & 63);
  int g = lane >> 4;
  const u64* basep = adjbits + (size_t)b * NN * 16;
  for (int n = g; n < cnt; n += 4) {
    int j = list[n];
    acc |= basep[(size_t)j * 16 + w];
  }
  acc |= __shfl_xor(acc, 16, 64);
  acc |= __shfl_xor(acc, 32, 64);
  if (lane < 16) neighbits[(size_t)row * 16 + lane] = acc;
}

// ------------------------------------------------------------- attention
// Block = (b, chunk of 16 rows, j-half of 512). 4 waves x 4 rows each.
// Direct exp (scores bounded; clamp 85, masked -> -100). NO min-waves
// launch_bounds arg: r6 (256,3) -> VGPR 84 + 584 MB spill; r7 (256,4) ->
// VGPR 64 + 51 MB spill. Leave the allocator alone; occupancy comes from
// the 32 KB LDS (4-5 blocks/CU).
__global__ __launch_bounds__(256) void k_attn(
    const void* __restrict__ feats, const void* __restrict__ coors,
    const void* __restrict__ Wq, const void* __restrict__ Wk,
    const void* __restrict__ Wv, const void* __restrict__ Wo,
    const void* __restrict__ wr1, const void* __restrict__ br1,
    const void* __restrict__ wr2, const void* __restrict__ br2,
    const u64* __restrict__ neighbits, float* __restrict__ rowAgg) {
  __shared__ __align__(16) float4 kvL[512 * 3];  // 24 KB: k0..k4,v0..v4,pad,pad
  __shared__ float coL[512 * 3];                 // 6 KB
  __shared__ float wqL[25], wkL[25], wvL[25], woL[25];
  __shared__ float qL[16 * DD], ciL[16 * 3];
  __shared__ float wrL[3][RH];
  __shared__ float sConst[2];  // [0]=C (collapsed radial), [1]=b_r2
  __shared__ int sFast;
  __shared__ int sCnt[4];
  int bi = blockIdx.x;
  int b = bi >> 7, rem = bi & 127, chunk = rem >> 1, half = rem & 1;
  int j0 = half * 512;
  int tid = threadIdx.x;
  // ---- per-block feats dtype probe (256 words, ballot majority) ----
  {
    u32 x = ((const u32*)feats)[tid];
    u32 lo = x & 0xFFFFu;
    int e = (int)((lo >> 7) & 0xFFu);
    bool insane = !(lo == 0u || (e >= 90 && e <= 150));
    u64 m = __ballot(insane);
    if ((tid & 63) == 0) sCnt[tid >> 6] = (int)__popcll(m);
  }
  __syncthreads();
  bool f32 = (sCnt[0] + sCnt[1] + sCnt[2] + sCnt[3]) > 64;
  if (tid < 25) {
    wqL[tid] = ldf(Wq, tid, f32);
    wkL[tid] = ldf(Wk, tid, f32);
    wvL[tid] = ldf(Wv, tid, f32);
    woL[tid] = ldf(Wo, tid, f32);
  }
  if (tid >= 64 && tid < 64 + RH) {
    int h = tid - 64;
    wrL[0][h] = ldf(wr1, h, f32);
    wrL[1][h] = ldf(br1, h, f32);
    wrL[2][h] = ldf(wr2, h, f32);
  }
  if (tid == 96) {
    float c = 0.0f;
    int ok = 1;
    #pragma unroll
    for (int h = 0; h < RH; ++h) {
      float w1h = ldf(wr1, h, f32);
      if (ldf(br1, h, f32) != 0.0f) ok = 0;
      if (w1h > 0.0f) c += w1h * ldf(wr2, h, f32);
    }
    sConst[0] = c;
    sConst[1] = ldf(br2, 0, f32);
    sFast = ok;
  }
  __syncthreads();
  // stage k, v' = (f@Wv)@Wo and co for this j-half
  for (int n = tid; n < 512; n += 256) {
    long long node = (long long)b * NN + j0 + n;
    float f0 = ldf(feats, node * DD + 0, f32), f1 = ldf(feats, node * DD + 1, f32),
          f2 = ldf(feats, node * DD + 2, f32), f3 = ldf(feats, node * DD + 3, f32),
          f4 = ldf(feats, node * DD + 4, f32);
    float k[DD], tv[DD], v[DD];
    #pragma unroll
    for (int e = 0; e < DD; ++e) {
      k[e] = f0 * wkL[e] + f1 * wkL[5 + e] + f2 * wkL[10 + e] + f3 * wkL[15 + e] +
             f4 * wkL[20 + e];
      tv[e] = f0 * wvL[e] + f1 * wvL[5 + e] + f2 * wvL[10 + e] + f3 * wvL[15 + e] +
              f4 * wvL[20 + e];
    }
    #pragma unroll
    for (int e = 0; e < DD; ++e)
      v[e] = tv[0] * woL[e] + tv[1] * woL[5 + e] + tv[2] * woL[10 + e] +
             tv[3] * woL[15 + e] + tv[4] * woL[20 + e];
    kvL[n * 3 + 0] = make_float4(k[0], k[1], k[2], k[3]);
    kvL[n * 3 + 1] = make_float4(k[4], v[0], v[1], v[2]);
    kvL[n * 3 + 2] = make_float4(v[3], v[4], 0.f, 0.f);
  }
  for (int idx = tid; idx < 512 * 3; idx += 256)
    coL[idx] = ldf(coors, (long long)(b * NN + j0) * 3 + idx, f32);
  if (tid < 16) {
    long long row = (long long)b * NN + chunk * 16 + tid;
    float f0 = ldf(feats, row * DD + 0, f32), f1 = ldf(feats, row * DD + 1, f32),
          f2 = ldf(feats, row * DD + 2, f32), f3 = ldf(feats, row * DD + 3, f32),
          f4 = ldf(feats, row * DD + 4, f32);
    #pragma unroll
    for (int e = 0; e < DD; ++e)
      qL[tid * DD + e] = (f0 * wqL[e] + f1 * wqL[5 + e] + f2 * wqL[10 + e] +
                          f3 * wqL[15 + e] + f4 * wqL[20 + e]) * 0.4472135954999579f;
    #pragma unroll
    for (int c = 0; c < 3; ++c) ciL[tid * 3 + c] = ldf(coors, row * 3 + c, f32);
  }
  __syncthreads();

  int g = tid >> 6, lane = tid & 63;
  int i0 = chunk * 16 + g * 4;
  float q[4][DD], ci[4][3], l[4], A[4][DD];
  #pragma unroll
  for (int r = 0; r < 4; ++r) {
    #pragma unroll
    for (int e = 0; e < DD; ++e) q[r][e] = qL[(g * 4 + r) * DD + e];
    #pragma unroll
    for (int c = 0; c < 3; ++c) ci[r][c] = ciL[(g * 4 + r) * 3 + c];
    l[r] = 0.0f;
    #pragma unroll
    for (int e = 0; e < DD; ++e) A[r][e] = 0.0f;
  }
  const u64* nb = neighbits + ((size_t)(b * NN + i0)) * 16 + half * 8;
  float Cf = sConst[0], br2f = sConst[1];
  int fast = sFast;
  for (int it = 0; it < 8; ++it) {
    int j = it * 64 + lane;
    float4 ka = kvL[j * 3 + 0];
    float4 kb = kvL[j * 3 + 1];
    float4 kc = kvL[j * 3 + 2];
    float jx = coL[j * 3], jy = coL[j * 3 + 1], jz = coL[j * 3 + 2];
    if (fast) {
      #pragma unroll
      for (int r = 0; r < 4; ++r) {
        u64 nw = nb[(size_t)r * 16 + it];
        float cx = jx - ci[r][0], cy = jy - ci[r][1], cz = jz - ci[r][2];
        float dist = sqrtf(fmaf(cx, cx, fmaf(cy, cy, fmaf(cz, cz, 1e-8f))));
        float s = fmaf(q[r][0], ka.x, br2f);
        s = fmaf(q[r][1], ka.y, s);
        s = fmaf(q[r][2], ka.z, s);
        s = fmaf(q[r][3], ka.w, s);
        s = fmaf(q[r][4], kb.x, s);
        s = fmaf(Cf, dist, s);
        s = fminf(s, 85.0f);
        s = ((nw >> lane) & 1ull) ? s : -100.0f;
        float p = __expf(s);
        l[r] += p;
        A[r][0] = fmaf(p, kb.y, A[r][0]);
        A[r][1] = fmaf(p, kb.z, A[r][1]);
        A[r][2] = fmaf(p, kb.w, A[r][2]);
        A[r][3] = fmaf(p, kc.x, A[r][3]);
        A[r][4] = fmaf(p, kc.y, A[r][4]);
      }
    } else {
      #pragma unroll
      for (int r = 0; r < 4; ++r) {
        u64 nw = nb[(size_t)r * 16 + it];
        float cx = jx - ci[r][0], cy = jy - ci[r][1], cz = jz - ci[r][2];
        float dist = sqrtf(fmaf(cx, cx, fmaf(cy, cy, fmaf(cz, cz, 1e-8f))));
        float rb = br2f;
        #pragma unroll
        for (int h = 0; h < RH; ++h)
          rb += fmaxf(dist * wrL[0][h] + wrL[1][h], 0.0f) * wrL[2][h];
        float s = fmaf(q[r][0], ka.x, rb);
        s = fmaf(q[r][1], ka.y, s);
        s = fmaf(q[r][2], ka.z, s);
        s = fmaf(q[r][3], ka.w, s);
        s = fmaf(q[r][4], kb.x, s);
        s = fminf(s, 85.0f);
        s = ((nw >> lane) & 1ull) ? s : -100.0f;
        float p = __expf(s);
        l[r] += p;
        A[r][0] = fmaf(p, kb.y, A[r][0]);
        A[r][1] = fmaf(p, kb.z, A[r][1]);
        A[r][2] = fmaf(p, kb.w, A[r][2]);
        A[r][3] = fmaf(p, kc.x, A[r][3]);
        A[r][4] = fmaf(p, kc.y, A[r][4]);
      }
    }
  }
  #pragma unroll
  for (int msk = 1; msk < 64; msk <<= 1) {
    #pragma unroll
    for (int r = 0; r < 4; ++r) {
      l[r] += __shfl_xor(l[r], msk, 64);
      A[r][0] += __shfl_xor(A[r][0], msk, 64);
      A[r][1] += __shfl_xor(A[r][1], msk, 64);
      A[r][2] += __shfl_xor(A[r][2], msk, 64);
      A[r][3] += __shfl_xor(A[r][3], msk, 64);
      A[r][4] += __shfl_xor(A[r][4], msk, 64);
    }
  }
  if (lane == 0) {
    #pragma unroll
    for (int r = 0; r < 4; ++r) {
      float* o = rowAgg + (((size_t)(b * NN + i0 + r)) * 2 + half) * 6;
      o[0] = l[r];
      o[1] = A[r][0]; o[2] = A[r][1]; o[3] = A[r][2]; o[4] = A[r][3]; o[5] = A[r][4];
    }
  }
}

// --------------------------------------------------- finalize: pool + MLP
__global__ __launch_bounds__(256) void k_final(
    const void* __restrict__ feats, const float* __restrict__ rowAgg,
    const void* __restrict__ w1, const void* __restrict__ b1,
    const void* __restrict__ w2, const void* __restrict__ b2,
    float* __restrict__ out) {
  __shared__ float waveL[4][DD];
  __shared__ float poolL[DD];
  __shared__ float hL[128];
  __shared__ int sCnt[4];
  int b = blockIdx.x, tid = threadIdx.x;
  {
    u32 x = ((const u32*)feats)[tid];
    u32 lo = x & 0xFFFFu;
    int e = (int)((lo >> 7) & 0xFFu);
    bool insane = !(lo == 0u || (e >= 90 && e <= 150));
    u64 m = __ballot(insane);
    if ((tid & 63) == 0) sCnt[tid >> 6] = (int)__popcll(m);
  }
  __syncthreads();
  bool f32 = (sCnt[0] + sCnt[1] + sCnt[2] + sCnt[3]) > 64;
  float pe[DD] = {0.f, 0.f, 0.f, 0.f, 0.f};
  for (int n = tid; n < NN; n += 256) {
    const float* ag = rowAgg + ((size_t)(b * NN + n)) * 12;
    float l = ag[0] + ag[6];
    float inv = (l > 0.f) ? 1.0f / l : 0.0f;
    long long base = ((long long)b * NN + n) * DD;
    #pragma unroll
    for (int e = 0; e < DD; ++e)
      pe[e] += ldf(feats, base + e, f32) + (ag[1 + e] + ag[7 + e]) * inv;
  }
  #pragma unroll
  for (int off = 32; off >= 1; off >>= 1)
    #pragma unroll
    for (int e = 0; e < DD; ++e) pe[e] += __shfl_down(pe[e], off, 64);
  int wave = tid >> 6, lane = tid & 63;
  if (lane == 0)
    #pragma unroll
    for (int e = 0; e < DD; ++e) waveL[wave][e] = pe[e];
  __syncthreads();
  if (tid < DD)
    poolL[tid] = (waveL[0][tid] + waveL[1][tid] + waveL[2][tid] + waveL[3][tid]) *
                 (1.0f / 1024.0f);
  __syncthreads();
  if (tid < 128) {
    float acc = ldf(b1, tid, f32);
    #pragma unroll
    for (int d = 0; d < DD; ++d)
      acc = fmaf(poolL[d], ldf(w1, d * 128 + tid, f32), acc);
    hL[tid] = fmaxf(acc, 0.0f);
  }
  __syncthreads();
  if (tid < 3) {
    float s = ldf(b2, tid, f32);
    for (int j = 0; j < 128; ++j) s = fmaf(hL[j], ldf(w2, j * 3 + tid, f32), s);
    out[b * 3 + tid] = s;
  }
}

// ---------------------------------------------------------------- launch
extern "C" void kernel_launch(void* const* d_in, const int* in_sizes, int n_in,
                              void* d_out, int out_size, void* d_ws, size_t ws_size,
                              hipStream_t stream) {
  const void* adj = d_in[2];
  float* out = (float*)d_out;

  char* w = (char*)d_ws;
  const size_t BITS_BYTES = (size_t)BB * NN * 16 * sizeof(u64);  // 2 MiB
  u64* adjbits = (u64*)(w + 512);
  u64* neighbits = (u64*)(w + 512 + BITS_BYTES);
  float* rowAgg = (float*)(w + 512 + 2 * BITS_BYTES);  // B*N*2*6 f32 = 768 KiB

  k_pack<<<BB * NN * 16 / 256, 256, 0, stream>>>(adj, adjbits);
  k_twohop<<<BB * NN / 4, 256, 0, stream>>>(adjbits, neighbits);
  k_attn<<<BB * 128, 256, 0, stream>>>(d_in[0], d_in[1], d_in[3], d_in[4], d_in[5],
                                       d_in[6], d_in[7], d_in[8], d_in[9], d_in[10],
                                       neighbits, rowAgg);
  k_final<<<BB, 256, 0, stream>>>(d_in[0], rowAgg, d_in[11], d_in[12],
                                  d_in[13], d_in[14], out);
}